// Round 1
// baseline (25.951 us; speedup 1.0000x reference)
//
#include <hip/hip_runtime.h>

// Dist_Conv2D: out[b,f,h,w] = max_{c,i,j} |W[f, c*9+i*3+j] - x_pad[b,c,h+i,w+j]| + bias[f]
// x: (4,16,64,64) f32, W: (64,144) f32, bias: (64,) f32, out: (4,64,64,64) f32
// replicate pad 1 on each side of H,W.

#define BB 4
#define CC 16
#define HH 64
#define WW 64
#define FF 64
#define FCHUNK 8

__global__ __launch_bounds__(256) void dist_conv2d_kernel(
    const float* __restrict__ x,
    const float* __restrict__ wgt,
    const float* __restrict__ bias,
    float* __restrict__ out) {
    int tid = blockIdx.x * blockDim.x + threadIdx.x;
    // tid = ((fc * BB + b) * HH + h) * WW + w ; lanes vary only in w -> f,b,h wave-uniform
    int w  = tid & 63;
    int h  = (tid >> 6) & 63;
    int b  = (tid >> 12) & 3;
    int fc = tid >> 14;          // 0..7
    int f0 = fc * FCHUNK;

    // replicate-pad clamped neighbor indices
    int r0 = h - 1; if (r0 < 0) r0 = 0;
    int r2 = h + 1; if (r2 > HH - 1) r2 = HH - 1;
    int c0 = w - 1; if (c0 < 0) c0 = 0;
    int c2 = w + 1; if (c2 > WW - 1) c2 = WW - 1;
    int row0 = r0 * WW, row1 = h * WW, row2 = r2 * WW;

    float dist[FCHUNK];
#pragma unroll
    for (int i = 0; i < FCHUNK; ++i) dist[i] = 0.0f;  // |.| >= 0, safe identity

    const float* xb = x + b * (CC * HH * WW);
    for (int c = 0; c < CC; ++c) {
        const float* xc = xb + c * (HH * WW);
        float p[9];
        p[0] = xc[row0 + c0]; p[1] = xc[row0 + w]; p[2] = xc[row0 + c2];
        p[3] = xc[row1 + c0]; p[4] = xc[row1 + w]; p[5] = xc[row1 + c2];
        p[6] = xc[row2 + c0]; p[7] = xc[row2 + w]; p[8] = xc[row2 + c2];
#pragma unroll
        for (int fi = 0; fi < FCHUNK; ++fi) {
            const float* wrow = wgt + (f0 + fi) * (CC * 9) + c * 9;  // wave-uniform -> s_load
#pragma unroll
            for (int k = 0; k < 9; ++k) {
                float d = p[k] - wrow[k];
                dist[fi] = fmaxf(dist[fi], fabsf(d));  // v_max_f32 with |d| modifier
            }
        }
    }

    float* ob = out + ((b * FF + f0) * HH + h) * WW + w;
#pragma unroll
    for (int fi = 0; fi < FCHUNK; ++fi) {
        ob[fi * (HH * WW)] = dist[fi] + bias[f0 + fi];
    }
}

extern "C" void kernel_launch(void* const* d_in, const int* in_sizes, int n_in,
                              void* d_out, int out_size, void* d_ws, size_t ws_size,
                              hipStream_t stream) {
    const float* x    = (const float*)d_in[0];
    const float* wgt  = (const float*)d_in[1];
    const float* bias = (const float*)d_in[2];
    float* out = (float*)d_out;

    const int total = (FF / FCHUNK) * BB * HH * WW;  // 131072 threads
    dist_conv2d_kernel<<<total / 256, 256, 0, stream>>>(x, wgt, bias, out);
}